// Round 3
// baseline (305.056 us; speedup 1.0000x reference)
//
#include <hip/hip_runtime.h>

// Broadcast a float from lane l via v_readlane (VALU pipe, uniform result).
__device__ __forceinline__ float rdlane(float v, int l) {
    return __int_as_float(__builtin_amdgcn_readlane(__float_as_int(v), l));
}

// max(x, dpp_shuffle(x)) — one butterfly step of a 64-lane max reduction.
template <int CTRL>
__device__ __forceinline__ float dpp_max_step(float x) {
    int t = __builtin_amdgcn_update_dpp(0, __float_as_int(x), CTRL, 0xF, 0xF, true);
    return fmaxf(x, __int_as_float(t));
}

// Full 64-lane max; result valid in lane 63 (invalid DPP lanes inject 0.0,
// harmless here because the max is an abs-value, always >= 0).
__device__ __forceinline__ float wave_max_to_lane63(float x) {
    x = dpp_max_step<0xB1>(x);   // quad_perm [1,0,3,2]  (xor 1)
    x = dpp_max_step<0x4E>(x);   // quad_perm [2,3,0,1]  (xor 2)
    x = dpp_max_step<0x141>(x);  // row_half_mirror      (xor within 8)
    x = dpp_max_step<0x140>(x);  // row_mirror           (xor within 16)
    x = dpp_max_step<0x142>(x);  // row_bcast15          (16 -> 32)
    x = dpp_max_step<0x143>(x);  // row_bcast31          (32 -> 64)
    return x;                    // lane 63 holds the global max
}

// One wave = one 64x64 matrix, lane i owns ROW i in registers A[0..63].
// Block = 128 threads: wave 0 -> spin-up matrix, wave 1 -> spin-dn matrix.
//
// __launch_bounds__(128, 2): cap at 2 waves/EU -> 256-VGPR budget. Round-2
// evidence: with the default budget the allocator split A[] into AGPRs
// (VGPR_Count=36), and since v_readlane can't source an AGPR every inner-loop
// step paid v_accvgpr_read/write traffic (~3x instruction inflation, 18k vs
// 6k instrs/wave deduced from VALUBusy*dur). ~110 regs fit the 256 cap ->
// pure-VGPR frame, same-or-better occupancy than the 104-unified-reg split.
__global__ __launch_bounds__(128, 2) void slater_logdet_kernel(
        const float* __restrict__ rs, const float* __restrict__ log_alpha_p,
        float* __restrict__ out) {
    const int b    = blockIdx.x;
    const int tid  = threadIdx.x;
    const int wave = tid >> 6;   // 0 = up, 1 = dn
    const int lane = tid & 63;

    const float Lbox = 10.0f;
    const float PI_F = 3.14159265358979323846f;

    float alpha = __expf(log_alpha_p[0]);
    alpha = fminf(fmaxf(alpha, 0.5f / (Lbox * Lbox)), 200.0f / (Lbox * Lbox));

    // Electron position for this lane (row index = electron index).
    const float* rp = rs + (size_t)b * 384 + (size_t)(wave * 64 + lane) * 3;
    float x = rp[0], y = rp[1], z = rp[2];

    float sx, cx, sy, cy, sz, cz;
    __sincosf(x * (PI_F / Lbox), &sx, &cx);
    __sincosf(y * (PI_F / Lbox), &sy, &cy);
    __sincosf(z * (PI_F / Lbox), &sz, &cz);

    // Separable build: Phi[i][j] = ex[mx]*ey[my]*ez[mz], j = mx*16+my*4+mz.
    // Only 12 exps + ~80 muls per lane.
    const float off = wave ? 0.5f : 0.0f;
    const float LPI = Lbox / PI_F;
    float ex[4], ey[4], ez[4];
#pragma unroll
    for (int m = 0; m < 4; ++m) {
        float sp, cp;
        __sincosf((PI_F * 0.25f) * ((float)m + off), &sp, &cp);
        float dx = LPI * (sx * cp - cx * sp);
        float dy = LPI * (sy * cp - cy * sp);
        float dz = LPI * (sz * cp - cz * sp);
        ex[m] = __expf(-alpha * dx * dx);
        ey[m] = __expf(-alpha * dy * dy);
        ez[m] = __expf(-alpha * dz * dz);
    }
    float exy[16];
#pragma unroll
    for (int q = 0; q < 16; ++q) exy[q] = ex[q >> 2] * ey[q & 3];
    float A[64];
#pragma unroll
    for (int j = 0; j < 64; ++j) A[j] = exy[j >> 2] * ez[j & 3];

    // LU with partial pivoting, row-owner layout, NO physical row swap:
    // pivot rows stay in their lane; flag = -inf marks them dead so the
    // argmax never selects them again. det sign is irrelevant (log|det|).
    float flag   = 0.0f;   // 0 while alive, -inf once used as pivot row
    float logdet = 0.0f;
    const int lane_v = lane;
#pragma unroll
    for (int k = 0; k < 64; ++k) {
        // key = |A[k]| for alive rows, -inf for dead rows
        float key  = fabsf(A[k]) + flag;
        float gmax = rdlane(wave_max_to_lane63(key), 63);
        unsigned long long ball = __ballot(key == gmax);
        int p = (int)(__ffsll(ball) - 1);          // pivot row's physical lane

        float pv  = rdlane(A[k], p);
        float inv = __builtin_amdgcn_rcpf(pv);
        inv = inv * (2.0f - pv * inv);             // 1 Newton step (~0.5 ulp)
        logdet += __logf(fabsf(pv));

        // Mark pivot row dead for future argmaxes.
        flag = (lane_v == p) ? -__builtin_huge_valf() : flag;

        // One multiplier per lane in a single op; lane p gets m~=1 and
        // self-annihilates (row never read again), dead lanes have A[k]=~0.
        float m = A[k] * inv;
#pragma unroll
        for (int j = k + 1; j < 64; ++j) {
            float s = rdlane(A[j], p);             // pivot-row elem -> SGPR
            A[j] = __builtin_fmaf(-m, s, A[j]);    // all 64 rows at once
        }
    }

    // logdet is lane-uniform. Combine the two spins.
    __shared__ float partial[2];
    if (lane == 0) partial[wave] = logdet;
    __syncthreads();
    if (tid == 0) out[b] = partial[0] + partial[1];
}

extern "C" void kernel_launch(void* const* d_in, const int* in_sizes, int n_in,
                              void* d_out, int out_size, void* d_ws, size_t ws_size,
                              hipStream_t stream) {
    const float* rs = (const float*)d_in[0];
    const float* la = (const float*)d_in[1];
    float* out      = (float*)d_out;
    slater_logdet_kernel<<<out_size, 128, 0, stream>>>(rs, la, out);
}